// Round 1
// baseline (50.489 us; speedup 1.0000x reference)
//
#include <hip/hip_runtime.h>
#include <cstdint>

// Problem constants (B=1024, S=4096, P=512)
constexpr int B_ = 1024;
constexpr int S_ = 4096;
constexpr int P_ = 512;

// ---------------------------------------------------------------------------
// Kernel A: scatter-add of ds into per-phone (sum, cnt) accumulators.
// 512 blocks x 256 threads x 32 elements = 4,194,304 = B*S exactly.
// Per-block LDS histogram, then global unsafeAtomicAdd into ws accumulators.
// ---------------------------------------------------------------------------
__global__ __launch_bounds__(256) void scatter_kernel(
    const int* __restrict__ idx, const float* __restrict__ ds,
    float* __restrict__ gsum, float* __restrict__ gcnt) {
  __shared__ float lsum[P_];
  __shared__ int   lcnt[P_];
  const int t = threadIdx.x;
  lsum[t] = 0.f; lsum[t + 256] = 0.f;
  lcnt[t] = 0;   lcnt[t + 256] = 0;
  __syncthreads();

  const size_t base = (size_t)blockIdx.x * 8192 + (size_t)t * 4;
#pragma unroll
  for (int k = 0; k < 8; ++k) {
    const size_t off = base + (size_t)k * 1024;
    int4   iv = *reinterpret_cast<const int4*>(idx + off);
    float4 dv = *reinterpret_cast<const float4*>(ds + off);
    atomicAdd(&lsum[iv.x], dv.x); atomicAdd(&lcnt[iv.x], 1);
    atomicAdd(&lsum[iv.y], dv.y); atomicAdd(&lcnt[iv.y], 1);
    atomicAdd(&lsum[iv.z], dv.z); atomicAdd(&lcnt[iv.z], 1);
    atomicAdd(&lsum[iv.w], dv.w); atomicAdd(&lcnt[iv.w], 1);
  }
  __syncthreads();

  unsafeAtomicAdd(&gsum[t],        lsum[t]);
  unsafeAtomicAdd(&gsum[t + 256],  lsum[t + 256]);
  unsafeAtomicAdd(&gcnt[t],        (float)lcnt[t]);
  unsafeAtomicAdd(&gcnt[t + 256],  (float)lcnt[t + 256]);
}

// ---------------------------------------------------------------------------
// Kernel B: finalize table + dn scalars. 1 block x 512 threads.
//   table[p] = touched ? (sum_in[p]+gsum[p]) / max(cnt_in[p]+gcnt[p],1) : dur_in[p]
//   dn_new   = has_26 ? (sum over bins 2..6) ratio : dn_in
//   scal[0]  = trunc(dn_new); scal[1] = trunc(dn_new) - trunc(rv*dn_new)
// Writes duration_new and dn_new into d_out tail (as float32).
// ---------------------------------------------------------------------------
__global__ __launch_bounds__(512) void finalize_kernel(
    const float* __restrict__ gsum, const float* __restrict__ gcnt,
    const float* __restrict__ sum_in, const float* __restrict__ cnt_in,
    const float* __restrict__ dur_in, const float* __restrict__ rv,
    const float* __restrict__ dn_in,
    float* __restrict__ table, float* __restrict__ scal,
    float* __restrict__ out_tail /* = d_out + B*S, holds 512+1 floats */) {
  __shared__ float s26[8], c26[8], rawc[8];
  const int p = threadIdx.x;

  const float sn = gsum[p] + sum_in[p];
  const float cn = gcnt[p] + cnt_in[p];
  const bool touched = gcnt[p] > 0.f;
  const float tv = touched ? sn / fmaxf(cn, 1.f) : dur_in[p];
  table[p]    = tv;
  out_tail[p] = tv;

  if (p >= 2 && p < 7) { s26[p] = sn; c26[p] = cn; rawc[p] = gcnt[p]; }
  __syncthreads();

  if (p == 0) {
    float ss = 0.f, cc = 0.f, rc = 0.f;
    for (int i = 2; i < 7; ++i) { ss += s26[i]; cc += c26[i]; rc += rawc[i]; }
    const bool has26 = rc > 0.f;
    const float dnn = has26 ? (ss / cc) : dn_in[0];
    out_tail[P_] = dnn;                       // d_out[B*S + 512] = dn_new
    const float dni = truncf(dnn);
    scal[0] = dni;
    scal[1] = dni - truncf(rv[0] * dnn);      // num
  }
}

// ---------------------------------------------------------------------------
// Kernel C: per-row gather + rescale. 1 block (256 thr) per row; 16 cols/thread.
// ---------------------------------------------------------------------------
__global__ __launch_bounds__(256) void eval_kernel(
    const int* __restrict__ idx, const float* __restrict__ table,
    const float* __restrict__ scal, const int* __restrict__ padp,
    float* __restrict__ out) {
  __shared__ float tbl[P_];
  __shared__ int   red_a[4], red_b[4], red_c[4];
  __shared__ int   bcast[3];  // n, dmax, denom

  const int t   = threadIdx.x;
  const int row = blockIdx.x;
  tbl[t]       = table[t];
  tbl[t + 256] = table[t + 256];
  const int pad = padp[0];
  __syncthreads();

  const int* __restrict__ rowidx = idx + (size_t)row * S_;
  int d[16];
  int jfirst = 0x7fffffff;
  int dmax   = 0x80000000;

#pragma unroll
  for (int k = 0; k < 4; ++k) {
    const int j0 = k * 1024 + t * 4;
    int4 iv = *reinterpret_cast<const int4*>(rowidx + j0);
    const int ivm[4] = {iv.x, iv.y, iv.z, iv.w};
#pragma unroll
    for (int m = 0; m < 4; ++m) {
      const int j = j0 + m;
      const int dd = (int)tbl[ivm[m]];  // trunc-toward-zero, values >= 0
      d[k * 4 + m] = dd;
      if (j >= 1) {
        if (ivm[m] == pad && j < jfirst) jfirst = j;
        if (dd > dmax) dmax = dd;
      }
    }
  }

  // phase-1 reduce: min(jfirst), max(dmax) over 256 threads
  const int wid = t >> 6, lane = t & 63;
  int a = jfirst, b = dmax;
#pragma unroll
  for (int o = 32; o > 0; o >>= 1) {
    a = min(a, __shfl_down(a, o));
    b = max(b, __shfl_down(b, o));
  }
  if (lane == 0) { red_a[wid] = a; red_b[wid] = b; }
  __syncthreads();
  if (t == 0) {
    int na = min(min(red_a[0], red_a[1]), min(red_a[2], red_a[3]));
    int nb = max(max(red_b[0], red_b[1]), max(red_b[2], red_b[3]));
    bcast[0] = (na == 0x7fffffff) ? 1 : na;   // n
    bcast[1] = nb;                            // row max dur (j>=1)
  }
  __syncthreads();
  const int n       = bcast[0];
  const int dmaxall = bcast[1];

  // phase-2 reduce: denom = sum of d[j] for 1 <= j < n
  int dsum = 0;
#pragma unroll
  for (int k = 0; k < 4; ++k) {
    const int j0 = k * 1024 + t * 4;
#pragma unroll
    for (int m = 0; m < 4; ++m) {
      const int j = j0 + m;
      if (j >= 1 && j < n) dsum += d[k * 4 + m];
    }
  }
#pragma unroll
  for (int o = 32; o > 0; o >>= 1) dsum += __shfl_down(dsum, o);
  if (lane == 0) red_c[wid] = dsum;
  __syncthreads();
  if (t == 0) bcast[2] = red_c[0] + red_c[1] + red_c[2] + red_c[3];
  __syncthreads();
  const int denom = bcast[2];

  const float dni = scal[0];
  const float num = scal[1];
  const float denomf = (float)denom;
  const float rc = (n == 1) ? 1.0f
                            : fminf(1.0f, num / (denomf > 0.f ? denomf : 1.0f));
  const int delta = max(dmaxall, 1);
  const int dur0  = max(1, (int)dni - delta);

  float* __restrict__ rowout = out + (size_t)row * S_;
#pragma unroll
  for (int k = 0; k < 4; ++k) {
    const int j0 = k * 1024 + t * 4;
    float4 ov;
    float* o = reinterpret_cast<float*>(&ov);
#pragma unroll
    for (int m = 0; m < 4; ++m) {
      const int j = j0 + m;
      const int dd = d[k * 4 + m];
      int v;
      if (j == 0)      v = dur0;
      else if (j < n)  v = max(1, (int)truncf(rc * (float)dd));
      else             v = dd;
      o[m] = (float)v;
    }
    *reinterpret_cast<float4*>(rowout + j0) = ov;
  }
}

// ---------------------------------------------------------------------------
extern "C" void kernel_launch(void* const* d_in, const int* in_sizes, int n_in,
                              void* d_out, int out_size, void* d_ws, size_t ws_size,
                              hipStream_t stream) {
  const int*   idx    = (const int*)d_in[0];
  const float* ds     = (const float*)d_in[1];
  const float* sum_in = (const float*)d_in[2];
  const float* cnt_in = (const float*)d_in[3];
  const float* dur_in = (const float*)d_in[4];
  const float* rv     = (const float*)d_in[5];
  const float* dn     = (const float*)d_in[6];
  const int*   pad    = (const int*)d_in[7];

  float* out = (float*)d_out;

  float* gsum  = (float*)d_ws;       // [512]
  float* gcnt  = gsum + P_;          // [512]
  float* table = gcnt + P_;          // [512]
  float* scal  = table + P_;         // [2] : dn_i, num

  // zero the atomic accumulators every call (ws state does not persist)
  hipMemsetAsync(d_ws, 0, 2 * P_ * sizeof(float), stream);

  scatter_kernel<<<512, 256, 0, stream>>>(idx, ds, gsum, gcnt);
  finalize_kernel<<<1, 512, 0, stream>>>(gsum, gcnt, sum_in, cnt_in, dur_in,
                                         rv, dn, table, scal,
                                         out + (size_t)B_ * S_);
  eval_kernel<<<1024, 256, 0, stream>>>(idx, table, scal, pad, out);
}